// Round 2
// baseline (238.264 us; speedup 1.0000x reference)
//
#include <hip/hip_runtime.h>

// Fused bilinear-2x-up -> leaky_relu(0.01) -> bilinear-0.5x-down
// == 3x3 clamped-edge stencil per output pixel:
//   up00 = .5625 e + .1875(b+d) + .0625 a   (etc. for the other 3 corners)
//   out  = 0.25 * sum(leaky_relu(up**))
//
// R3 structure: 2x2 output tile per thread, straight-line 16-load 4x4
// neighborhood.
//
// R4/R5: the two py block-groups that share each input row were landing on
// different XCDs (round-robin dispatch) -> second read of every shared row
// missed that XCD's L2 -> ~2x input fetch (402 MB total traffic at 6.4 TB/s
// == the observed ~63 us kernel portion). Changes:
//   1. XCD-chunked block swizzle: physical block p runs on XCD p%8; remap
//      so XCD k owns logical blocks [k*1024,(k+1)*1024) = 2 whole images
//      with py swept sequentially. Row reuse between adjacent py groups now
//      stays inside one XCD's 4 MiB L2 (working set ~1 MB).
//   2. Nontemporal stores: output is never re-read; don't let 128 MiB of
//      stores evict the input rows we're trying to keep in L2.
//      (R5 fix: builtin needs a native clang vector type, not HIP float4.)
//
// Layout: (16,128,128,128) fp32 NHWC; C=128 -> 32 float4 groups, lane takes
// one c4 group: 32 consecutive lanes load 512 B contiguous per (row,col).

#define NEG_SLOPE 0.01f

typedef float nativef4 __attribute__((ext_vector_type(4)));

__device__ __forceinline__ void nt_store(const float4& v, float4* p) {
    nativef4 nv;
    nv.x = v.x; nv.y = v.y; nv.z = v.z; nv.w = v.w;
    __builtin_nontemporal_store(nv, reinterpret_cast<nativef4*>(p));
}

__device__ __forceinline__ float lrelu(float v) {
    return fmaxf(v, NEG_SLOPE * v);  // slope < 1 => where(v>=0,v,s*v) == max
}

__device__ __forceinline__ float stencil(float a, float b, float c,
                                         float d, float e, float f,
                                         float g, float h, float i) {
    float up00 = 0.5625f * e + 0.1875f * (b + d) + 0.0625f * a;
    float up01 = 0.5625f * e + 0.1875f * (b + f) + 0.0625f * c;
    float up10 = 0.5625f * e + 0.1875f * (d + h) + 0.0625f * g;
    float up11 = 0.5625f * e + 0.1875f * (f + h) + 0.0625f * i;
    return 0.25f * (lrelu(up00) + lrelu(up01) + lrelu(up10) + lrelu(up11));
}

__device__ __forceinline__ float4 stencil4(const float4& a, const float4& b, const float4& c,
                                           const float4& d, const float4& e, const float4& f,
                                           const float4& g, const float4& h, const float4& i) {
    float4 o;
    o.x = stencil(a.x, b.x, c.x, d.x, e.x, f.x, g.x, h.x, i.x);
    o.y = stencil(a.y, b.y, c.y, d.y, e.y, f.y, g.y, h.y, i.y);
    o.z = stencil(a.z, b.z, c.z, d.z, e.z, f.z, g.z, h.z, i.z);
    o.w = stencil(a.w, b.w, c.w, d.w, e.w, f.w, g.w, h.w, i.w);
    return o;
}

__global__ __launch_bounds__(256) void ActivationFilter_kernel(
        const float4* __restrict__ in, float4* __restrict__ out) {
    // XCD-chunked swizzle: 8192 blocks, 8 XCDs, physical p -> XCD p%8.
    // Logical block l = (p%8)*1024 + p/8 gives XCD k the contiguous range
    // [k*1024,(k+1)*1024): images b={2k,2k+1}, py ascending within each.
    // Bijective since 8192 % 8 == 0.
    const int p = blockIdx.x;
    const int l = ((p & 7) << 10) + (p >> 3);

    // thread -> (b, y-pair, x-pair, c4): 16 * 64 * 64 * 32 = 2,097,152
    const int t  = (l << 8) + threadIdx.x;
    const int c4 = t & 31;
    const int px = (t >> 5) & 63;
    const int py = (t >> 11) & 63;
    const int b  = t >> 17;

    const int x0 = px << 1, y0 = py << 1;
    const int xm = max(x0 - 1, 0), x3 = min(x0 + 2, 127);
    const int ym = max(y0 - 1, 0), y3 = min(y0 + 2, 127);

    const int rb = b << 7;  // b*128
    // float4-unit address of (b, Y, X, c4)
#define ADDR(Y, X) (((((rb + (Y)) << 7) + (X)) << 5) + c4)

    // 4x4 clamped neighborhood: rows {ym, y0, y0+1, y3} x cols {xm, x0, x0+1, x3}
    const float4 v00 = in[ADDR(ym,   xm)], v01 = in[ADDR(ym,   x0)],
                 v02 = in[ADDR(ym,   x0+1)], v03 = in[ADDR(ym,   x3)];
    const float4 v10 = in[ADDR(y0,   xm)], v11 = in[ADDR(y0,   x0)],
                 v12 = in[ADDR(y0,   x0+1)], v13 = in[ADDR(y0,   x3)];
    const float4 v20 = in[ADDR(y0+1, xm)], v21 = in[ADDR(y0+1, x0)],
                 v22 = in[ADDR(y0+1, x0+1)], v23 = in[ADDR(y0+1, x3)];
    const float4 v30 = in[ADDR(y3,   xm)], v31 = in[ADDR(y3,   x0)],
                 v32 = in[ADDR(y3,   x0+1)], v33 = in[ADDR(y3,   x3)];

    nt_store(stencil4(v00, v01, v02, v10, v11, v12, v20, v21, v22), &out[ADDR(y0,   x0  )]);
    nt_store(stencil4(v01, v02, v03, v11, v12, v13, v21, v22, v23), &out[ADDR(y0,   x0+1)]);
    nt_store(stencil4(v10, v11, v12, v20, v21, v22, v30, v31, v32), &out[ADDR(y0+1, x0  )]);
    nt_store(stencil4(v11, v12, v13, v21, v22, v23, v31, v32, v33), &out[ADDR(y0+1, x0+1)]);
#undef ADDR
}

extern "C" void kernel_launch(void* const* d_in, const int* in_sizes, int n_in,
                              void* d_out, int out_size, void* d_ws, size_t ws_size,
                              hipStream_t stream) {
    const float4* in = (const float4*)d_in[0];
    float4* out = (float4*)d_out;
    // 2,097,152 threads -> 8192 blocks of 256
    ActivationFilter_kernel<<<dim3(8192), dim3(256), 0, stream>>>(in, out);
}

// Round 4
// 238.061 us; speedup vs baseline: 1.0009x; 1.0009x over previous
//
#include <hip/hip_runtime.h>

// Fused bilinear-2x-up -> leaky_relu(0.01) -> bilinear-0.5x-down
// == 3x3 clamped-edge stencil per output pixel:
//   up00 = .5625 e + .1875(b+d) + .0625 a   (etc. for the other 3 corners)
//   out  = 0.25 * sum(leaky_relu(up**))
//
// R6: reverted R4/R5's nontemporal stores (kernel 63->84.5 us regression;
// FETCH_SIZE=65MB proved there was no over-fetch to fix -- input is
// L2/L3-resident; counters showed latency-bound: 30% HBM, 33% VALU, 0
// conflicts) and the XCD swizzle (unswizzled mapping already gives XCD k a
// fixed vertical px-strip -> same-XCD row reuse).
//
// R7 == R6 resubmitted (R6 bench was an infra failure, not a kernel fail).
// Single change vs the proven 2x2 base: 2x4 output tile per thread.
// 24 loads / 8 outputs = 3 loads/output (was 4), 24 independent loads in
// flight per wave (was 16), half the waves. Straight-line, no loops.
//
// Layout: (16,128,128,128) fp32 NHWC; C=128 -> 32 float4 groups, lane takes
// one c4 group: 32 consecutive lanes load 512 B contiguous per (row,col).

#define NEG_SLOPE 0.01f

__device__ __forceinline__ float lrelu(float v) {
    return fmaxf(v, NEG_SLOPE * v);  // slope < 1 => where(v>=0,v,s*v) == max
}

__device__ __forceinline__ float stencil(float a, float b, float c,
                                         float d, float e, float f,
                                         float g, float h, float i) {
    float up00 = 0.5625f * e + 0.1875f * (b + d) + 0.0625f * a;
    float up01 = 0.5625f * e + 0.1875f * (b + f) + 0.0625f * c;
    float up10 = 0.5625f * e + 0.1875f * (d + h) + 0.0625f * g;
    float up11 = 0.5625f * e + 0.1875f * (f + h) + 0.0625f * i;
    return 0.25f * (lrelu(up00) + lrelu(up01) + lrelu(up10) + lrelu(up11));
}

__device__ __forceinline__ float4 stencil4(const float4& a, const float4& b, const float4& c,
                                           const float4& d, const float4& e, const float4& f,
                                           const float4& g, const float4& h, const float4& i) {
    float4 o;
    o.x = stencil(a.x, b.x, c.x, d.x, e.x, f.x, g.x, h.x, i.x);
    o.y = stencil(a.y, b.y, c.y, d.y, e.y, f.y, g.y, h.y, i.y);
    o.z = stencil(a.z, b.z, c.z, d.z, e.z, f.z, g.z, h.z, i.z);
    o.w = stencil(a.w, b.w, c.w, d.w, e.w, f.w, g.w, h.w, i.w);
    return o;
}

__global__ __launch_bounds__(256) void ActivationFilter_kernel(
        const float4* __restrict__ in, float4* __restrict__ out) {
    // thread -> (b, y-pair, x-quad, c4): 16 * 64 * 32 * 32 = 1,048,576
    const int t   = blockIdx.x * 256 + threadIdx.x;
    const int c4  = t & 31;
    const int px4 = (t >> 5) & 31;
    const int py  = (t >> 10) & 63;
    const int b   = t >> 16;

    const int x0 = px4 << 2, y0 = py << 1;
    const int xm = max(x0 - 1, 0), x5 = min(x0 + 4, 127);
    const int ym = max(y0 - 1, 0), y3 = min(y0 + 2, 127);

    const int rb = b << 7;  // b*128
    // float4-unit address of (b, Y, X, c4)
#define ADDR(Y, X) (((((rb + (Y)) << 7) + (X)) << 5) + c4)

    // 4x6 clamped neighborhood:
    // rows {ym, y0, y0+1, y3} x cols {xm, x0, x0+1, x0+2, x0+3, x5}
    const float4 v00 = in[ADDR(ym,   xm)],   v01 = in[ADDR(ym,   x0)],
                 v02 = in[ADDR(ym,   x0+1)], v03 = in[ADDR(ym,   x0+2)],
                 v04 = in[ADDR(ym,   x0+3)], v05 = in[ADDR(ym,   x5)];
    const float4 v10 = in[ADDR(y0,   xm)],   v11 = in[ADDR(y0,   x0)],
                 v12 = in[ADDR(y0,   x0+1)], v13 = in[ADDR(y0,   x0+2)],
                 v14 = in[ADDR(y0,   x0+3)], v15 = in[ADDR(y0,   x5)];
    const float4 v20 = in[ADDR(y0+1, xm)],   v21 = in[ADDR(y0+1, x0)],
                 v22 = in[ADDR(y0+1, x0+1)], v23 = in[ADDR(y0+1, x0+2)],
                 v24 = in[ADDR(y0+1, x0+3)], v25 = in[ADDR(y0+1, x5)];
    const float4 v30 = in[ADDR(y3,   xm)],   v31 = in[ADDR(y3,   x0)],
                 v32 = in[ADDR(y3,   x0+1)], v33 = in[ADDR(y3,   x0+2)],
                 v34 = in[ADDR(y3,   x0+3)], v35 = in[ADDR(y3,   x5)];

    out[ADDR(y0,   x0  )] = stencil4(v00, v01, v02, v10, v11, v12, v20, v21, v22);
    out[ADDR(y0,   x0+1)] = stencil4(v01, v02, v03, v11, v12, v13, v21, v22, v23);
    out[ADDR(y0,   x0+2)] = stencil4(v02, v03, v04, v12, v13, v14, v22, v23, v24);
    out[ADDR(y0,   x0+3)] = stencil4(v03, v04, v05, v13, v14, v15, v23, v24, v25);
    out[ADDR(y0+1, x0  )] = stencil4(v10, v11, v12, v20, v21, v22, v30, v31, v32);
    out[ADDR(y0+1, x0+1)] = stencil4(v11, v12, v13, v21, v22, v23, v31, v32, v33);
    out[ADDR(y0+1, x0+2)] = stencil4(v12, v13, v14, v22, v23, v24, v32, v33, v34);
    out[ADDR(y0+1, x0+3)] = stencil4(v13, v14, v15, v23, v24, v25, v33, v34, v35);
#undef ADDR
}

extern "C" void kernel_launch(void* const* d_in, const int* in_sizes, int n_in,
                              void* d_out, int out_size, void* d_ws, size_t ws_size,
                              hipStream_t stream) {
    const float4* in = (const float4*)d_in[0];
    float4* out = (float4*)d_out;
    // 1,048,576 threads -> 4096 blocks of 256
    ActivationFilter_kernel<<<dim3(4096), dim3(256), 0, stream>>>(in, out);
}